// Round 15
// baseline (36.186 us; speedup 1.0000x reference)
//
#include <hip/hip_runtime.h>
#include <hip/hip_bf16.h>

// Problem constants: B=32768, D=768, C=200.
#define NROWS  32768
#define DIMS   768
#define NC     200
#define CPAD   256
#define KSUB   32                // cnb2 k-block granularity (layout unchanged)
#define KSTEP2 64                // K per phase
#define NSTEP2 (DIMS / KSTEP2)   // 12 phases
#define ROWSB  64                // M-tile rows per block -> grid 512

typedef __attribute__((ext_vector_type(8))) short short8;   // 8 bf16
typedef __attribute__((ext_vector_type(4))) float f32x4;

#define WAITV4 asm volatile("s_waitcnt vmcnt(4)" ::: "memory")
#define WAITL0 asm volatile("s_waitcnt lgkmcnt(0)" ::: "memory")
#define BAR    __builtin_amdgcn_s_barrier()

__device__ __forceinline__ unsigned pk_bf16(float lo, float hi) {
  union { __hip_bfloat162 h; unsigned u; } c;
  c.h = __float22bfloat162_rn(make_float2(lo, hi));
  return c.u;
}

// Kernel 1 (unchanged): L2-normalize centers -> bf16, K-blocked by 32:
// (c,d) -> cnb2[(d>>5)*CPAD*KSUB + c*KSUB + (d&31)]; rows >= NC zero. Zeroes out.
__global__ __launch_bounds__(256) void prep_centers_k(const float* __restrict__ centers,
                                                      short* __restrict__ cnb2,
                                                      float* __restrict__ out) {
  const int c = blockIdx.x;
  const int tid = threadIdx.x;
  if (c == 0 && tid == 0) out[0] = 0.f;
  if (c >= NC) {
    for (int d = tid; d < DIMS; d += 256)
      cnb2[(d >> 5) * (CPAD * KSUB) + c * KSUB + (d & 31)] = 0;
    return;
  }
  float ssq = 0.f;
  for (int d = tid; d < DIMS; d += 256) {
    float v = centers[c * DIMS + d];
    ssq += v * v;
  }
#pragma unroll
  for (int off = 32; off > 0; off >>= 1) ssq += __shfl_down(ssq, off);
  __shared__ float red[4];
  const int wid = tid >> 6, lane = tid & 63;
  if (lane == 0) red[wid] = ssq;
  __syncthreads();
  const float tot = red[0] + red[1] + red[2] + red[3];
  const float inv = 1.f / fmaxf(sqrtf(tot), 1e-8f);
  for (int d = tid; d < DIMS; d += 256) {
    const float v = centers[c * DIMS + d] * inv;
    union { __hip_bfloat16 h; short s; } cv;
    cv.h = __float2bfloat16(v);
    cnb2[(d >> 5) * (CPAD * KSUB) + c * KSUB + (d & 31)] = cv.s;
  }
}

// Kernel 2: producer-consumer with KSTEP=64 (12 phases).
//  - Consumers (waves 0-3): 64x64 tile, acc[4][4]; per phase two 16-MFMA
//    setprio clusters (k-halves); B staggered-reload direct from L2 cnb2.
//  - Producers (waves 4-7): 4xfloat4 depth-2 slots, cvt, 2 ds_write_b128.
//  - A LDS tile [2][64][64] shorts (128 B rows) with per-row quad swizzle
//    q ^ (row&7) on write and read (breaks the 128B-stride bank trap).
// MFMA frag mapping (verified rounds 2-14): A lane=A[m][kg*8+j];
// B lane=B[kg*8+j][m]; D: col=m, row=kg*4+reg.
__global__ __launch_bounds__(512, 4) void cos_loss_k(
    const float* __restrict__ feats,
    const short* __restrict__ cnb2,
    const int* __restrict__ labels,
    const int* __restrict__ labelled,
    float* __restrict__ out) {
  const int tid = threadIdx.x;
  const int wid = tid >> 6;          // 0-3 consumers, 4-7 producers
  const int lane = tid & 63;
  const int rowBase = blockIdx.x * ROWSB;

  __shared__ short As[2][ROWSB][64];   // 16 KB, dbuf, swizzled quads
  __shared__ float invs[ROWSB];
  __shared__ float l1part[4][ROWSB];
  __shared__ float alpart[4][ROWSB];

  if (wid < 4) {
    // =========================== CONSUMER ===========================
    const int m = lane & 15;
    const int kg = lane >> 4;
    const int sw = m & 7;
    const int o0 = ((kg ^ sw)) * 8;          // k-half 0 quad offset (shorts)
    const int o1 = ((kg ^ sw) ^ 4) * 8;      // k-half 1 quad offset
    const short* bp = cnb2 + (size_t)(wid * 64 + m) * KSUB + kg * 8;

    f32x4 acc[4][4];
#pragma unroll
    for (int mi = 0; mi < 4; ++mi)
#pragma unroll
      for (int ni = 0; ni < 4; ++ni) acc[mi][ni] = (f32x4){0.f, 0.f, 0.f, 0.f};

    short8 B0[4], B1[4];   // k-half 0 / 1 frags for the 4 ni tiles

#define BLD0(ni, s) B0[ni] = *(const short8*)(bp + (size_t)(2*(s)    ) * (CPAD*KSUB) + (ni) * (16*KSUB))
#define BLD1(ni, s) B1[ni] = *(const short8*)(bp + (size_t)(2*(s) + 1) * (CPAD*KSUB) + (ni) * (16*KSUB))

    // prologue: B for step 0 (8 loads); A buf0 published at the barrier
    BLD0(0,0); BLD0(1,0); BLD0(2,0); BLD0(3,0);
    BLD1(0,0); BLD1(1,0); BLD1(2,0); BLD1(3,0);
    BAR;   // barrier 0

#define PHASEC(p, ab) do {                                               \
    const int sn_ = ((p) + 1 < NSTEP2) ? (p) + 1 : NSTEP2 - 1;           \
    short8 af[4];                                                        \
    /* ---- k-half 0 ---- */                                             \
    _Pragma("unroll")                                                    \
    for (int mi = 0; mi < 4; ++mi)                                       \
      af[mi] = *(const short8*)(&As[(ab)][mi * 16 + m][o0]);             \
    __builtin_amdgcn_s_setprio(1);                                       \
    _Pragma("unroll")                                                    \
    for (int ni = 0; ni < 4; ++ni) {                                     \
      _Pragma("unroll")                                                  \
      for (int mi = 0; mi < 4; ++mi)                                     \
        acc[mi][ni] = __builtin_amdgcn_mfma_f32_16x16x32_bf16(           \
            af[mi], B0[ni], acc[mi][ni], 0, 0, 0);                       \
      BLD0(ni, sn_);                                                     \
    }                                                                    \
    __builtin_amdgcn_s_setprio(0);                                       \
    /* ---- k-half 1 ---- */                                             \
    _Pragma("unroll")                                                    \
    for (int mi = 0; mi < 4; ++mi)                                       \
      af[mi] = *(const short8*)(&As[(ab)][mi * 16 + m][o1]);             \
    __builtin_amdgcn_s_setprio(1);                                       \
    _Pragma("unroll")                                                    \
    for (int ni = 0; ni < 4; ++ni) {                                     \
      _Pragma("unroll")                                                  \
      for (int mi = 0; mi < 4; ++mi)                                     \
        acc[mi][ni] = __builtin_amdgcn_mfma_f32_16x16x32_bf16(           \
            af[mi], B1[ni], acc[mi][ni], 0, 0, 0);                       \
      BLD1(ni, sn_);                                                     \
    }                                                                    \
    __builtin_amdgcn_s_setprio(0);                                       \
    BAR;                                                                 \
  } while (0)

    for (int p = 0; p < NSTEP2; p += 2) {
      PHASEC(p, 0);
      PHASEC(p + 1, 1);
    }
#undef BLD0
#undef BLD1
#undef PHASEC

    BAR;   // barrier 13: invs published by producers

    // epilogue: per-row l1 and label-|cos|
#pragma unroll
    for (int mi = 0; mi < 4; ++mi) {
      float l1r[4] = {0.f, 0.f, 0.f, 0.f};
      float alr[4] = {0.f, 0.f, 0.f, 0.f};
      float iv[4];
      int labr[4];
#pragma unroll
      for (int r = 0; r < 4; ++r) {
        const int row = mi * 16 + kg * 4 + r;
        iv[r] = invs[row];
        labr[r] = labels[rowBase + row];
      }
#pragma unroll
      for (int ni = 0; ni < 4; ++ni) {
        const int col = wid * 64 + ni * 16 + m;
#pragma unroll
        for (int r = 0; r < 4; ++r) {
          const float a = fabsf(acc[mi][ni][r] * iv[r]);
          l1r[r] += a;
          if (col == labr[r]) alr[r] += a;
        }
      }
#pragma unroll
      for (int r = 0; r < 4; ++r) {
#pragma unroll
        for (int off = 1; off < 16; off <<= 1) {
          l1r[r] += __shfl_xor(l1r[r], off);
          alr[r] += __shfl_xor(alr[r], off);
        }
      }
      if (m == 0) {
#pragma unroll
        for (int r = 0; r < 4; ++r) {
          l1part[wid][mi * 16 + kg * 4 + r] = l1r[r];
          alpart[wid][mi * 16 + kg * 4 + r] = alr[r];
        }
      }
    }
  } else {
    // =========================== PRODUCER ===========================
    const int pt = (wid - 4) * 64 + lane;    // 0..255
    const int arow = pt >> 2;                // 4 thr/row
    const int ac   = pt & 3;                 // 16-float chunk within the 64-k slice
    const int rs   = arow & 7;               // row swizzle
    const int lq   = ac * 2;                 // logical quads lq, lq+1
    const float* asrc = feats + (size_t)(rowBase + arow) * DIMS + ac * 16;
    const int pq0 = (lq ^ rs) * 8;           // phys short offsets
    const int pq1 = ((lq + 1) ^ rs) * 8;

    float ssq = 0.f;
    // depth-2 slots, 4 float4 each (static names)
    float4 S0a, S0b, S0c, S0d, S1a, S1b, S1c, S1d;

#define LOADA(P, s) do {                                                 \
    const float* ap_ = asrc + (s) * KSTEP2;                              \
    P##a = *(const float4*)(ap_);                                        \
    P##b = *(const float4*)(ap_ + 4);                                    \
    P##c = *(const float4*)(ap_ + 8);                                    \
    P##d = *(const float4*)(ap_ + 12);                                   \
  } while (0)

#define WRITEA(P, buf, guard) do {                                       \
    if (guard) {                                                         \
      ssq += P##a.x*P##a.x + P##a.y*P##a.y + P##a.z*P##a.z + P##a.w*P##a.w; \
      ssq += P##b.x*P##b.x + P##b.y*P##b.y + P##b.z*P##b.z + P##b.w*P##b.w; \
      ssq += P##c.x*P##c.x + P##c.y*P##c.y + P##c.z*P##c.z + P##c.w*P##c.w; \
      ssq += P##d.x*P##d.x + P##d.y*P##d.y + P##d.z*P##d.z + P##d.w*P##d.w; \
    }                                                                    \
    union { short8 s8; unsigned u[4]; } q0_, q1_;                        \
    q0_.u[0] = pk_bf16(P##a.x, P##a.y); q0_.u[1] = pk_bf16(P##a.z, P##a.w); \
    q0_.u[2] = pk_bf16(P##b.x, P##b.y); q0_.u[3] = pk_bf16(P##b.z, P##b.w); \
    q1_.u[0] = pk_bf16(P##c.x, P##c.y); q1_.u[1] = pk_bf16(P##c.z, P##c.w); \
    q1_.u[2] = pk_bf16(P##d.x, P##d.y); q1_.u[3] = pk_bf16(P##d.z, P##d.w); \
    *(short8*)(&As[(buf)][arow][pq0]) = q0_.s8;                          \
    *(short8*)(&As[(buf)][arow][pq1]) = q1_.s8;                          \
  } while (0)

#define CLMP(x) (((x) < NSTEP2) ? (x) : NSTEP2 - 1)

    // prologue: load steps 0,1; publish step 0 -> buf0
    LOADA(S0, 0);
    LOADA(S1, 1);
    WAITV4;            // S0 ready; S1 in flight
    WRITEA(S0, 0, true);
    WAITL0;
    BAR;   // barrier 0

    for (int p = 0; p < NSTEP2; p += 2) {
      // phase p: prefetch p+2 into S0; publish step p+1 (S1) -> buf1
      LOADA(S0, CLMP(p + 2));
      WAITV4;          // S1 (step p+1) ready; S0 in flight
      WRITEA(S1, 1, (p + 1 < NSTEP2));
      WAITL0;
      BAR;
      // phase p+1: prefetch p+3 into S1; publish step p+2 (S0) -> buf0
      LOADA(S1, CLMP(p + 3));
      WAITV4;          // S0 (step p+2) ready
      WRITEA(S0, 0, (p + 2 < NSTEP2));
      WAITL0;
      BAR;
    }
#undef LOADA
#undef WRITEA
#undef CLMP

    // row inverse norms: reduce over the 4 staging lanes of each row
    ssq += __shfl_xor(ssq, 1);
    ssq += __shfl_xor(ssq, 2);
    if ((lane & 3) == 0) invs[arow] = 1.f / fmaxf(sqrtf(ssq), 1e-8f);
    WAITL0;
    BAR;   // barrier 13: invs published
  }

  __syncthreads();     // l1part/alpart published + full drain

  if (tid < ROWSB) {
    const float L = l1part[0][tid] + l1part[1][tid] + l1part[2][tid] + l1part[3][tid];
    const float A = alpart[0][tid] + alpart[1][tid] + alpart[2][tid] + alpart[3][tid];
    float c = labelled[rowBase + tid] ? (L - 2.f * A) / fmaxf(L, 1e-12f) : 0.f;
#pragma unroll
    for (int off = 1; off < 64; off <<= 1) c += __shfl_xor(c, off);
    if (tid == 0) atomicAdd(out, c);
  }
}

extern "C" void kernel_launch(void* const* d_in, const int* in_sizes, int n_in,
                              void* d_out, int out_size, void* d_ws, size_t ws_size,
                              hipStream_t stream) {
  const float* feats = (const float*)d_in[0];
  const float* centers = (const float*)d_in[1];
  const int* labels = (const int*)d_in[2];
  const int* labelled = (const int*)d_in[3];
  float* out = (float*)d_out;
  short* cnb2 = (short*)d_ws;  // [24][256][32] bf16 = 393216 B

  prep_centers_k<<<CPAD, 256, 0, stream>>>(centers, cnb2, out);
  cos_loss_k<<<NROWS / ROWSB, 512, 0, stream>>>(feats, cnb2, labels, labelled, out);
}